// Round 8
// baseline (194.155 us; speedup 1.0000x reference)
//
#include <hip/hip_runtime.h>

// ---------------- constants / ws layout (floats) ----------------
#define TT_ISTRIDE 672             // Tt per-i stride = 8 r * 84 padded j
#define TT_ELEMS (4 * 81 * 672)    // 217728
#define WS_HT 217728               // h_t: [4 a][36 q][8192 b] = 1179648 floats
#define WS_RIS (217728 + 1179648)  // risP: [4 iq][4 a][8192 b][8 r]
#define RIS_Q 262144

// Transpose T[a][q0][q1][q2][q3][r] -> Tt[a][i][r][84]; j in three 28-wide
// 16B-aligned thirds: col = jt*28 + (j - jt*27); slot 27 of each third = 0.
__global__ void t_transpose(const float* __restrict__ T, float* __restrict__ Tt) {
    int idx = blockIdx.x * 256 + threadIdx.x;
    if (idx >= TT_ELEMS) return;
    int col  = idx % 84;
    int t1   = idx / 84;
    int r    = t1 & 7;
    int rest = t1 / 8;  // a*81 + i
    int jt   = col / 28;
    int kk   = col - jt * 28;
    Tt[idx] = (kk < 27) ? T[rest * 648 + (jt * 27 + kk) * 8 + r] : 0.0f;
}

#define GLL(gsrc, ldst) __builtin_amdgcn_global_load_lds( \
    (const __attribute__((address_space(1))) void*)(gsrc), \
    (__attribute__((address_space(3))) void*)(ldst), 16, 0, 0)

#define KEEP(x) asm volatile("" : "+v"(x))

// ---------------- K1: phase X ----------------
// Block: 512 b x 1 (c,a); 256 thr = 4 waves = 4 h-quarters (64 h each), partial
// sums reduced through LDS. Lane owns 8 batches b = lane+64k. nh reg-staged into
// +1-padded LDS [512][33] (bank-conflict-free). U in LDS, broadcast b128 reads.
__global__ __launch_bounds__(256, 2) void k1_phasex(
    const float* __restrict__ nh, const float* __restrict__ U,
    const float* __restrict__ bi, float* __restrict__ h_t) {
    __shared__ float nh_s[512 * 33];   // 66 KB: [b][32 col + pad]
    __shared__ float u_s[2048];        // 8 KB:  [256 h][8 r]
    __shared__ float xp[512 * 9];      // 18 KB: [b][8 r + pad]
    const int t    = threadIdx.x;
    const int lane = t & 63;
    const int hq   = t >> 6;           // wave id = h-quarter
    const int orig = blockIdx.x;
    const int ca   = orig >> 4;        // bg = orig&15 -> 16 ca-siblings share XCD
    const int bg   = orig & 15;
    const int c    = ca >> 2;
    const int a    = ca & 3;
    const int b0   = bg << 9;

    // stage U[c][a][256][8] once (2048 f, f4 coalesced)
    {
        const float* Ub = U + (size_t)(((c << 2) + a) << 11);
        *(float4*)&u_s[t * 4]          = *(const float4*)(Ub + t * 4);
        *(float4*)&u_s[(t + 256) * 4]  = *(const float4*)(Ub + (t + 256) * 4);
    }

    float acc[8][8];   // [k batch][r]
    {
        const float* bp = bi + (((c << 2) + a) << 3);
        #pragma unroll
        for (int r = 0; r < 8; ++r) {
            float v = (hq == 0) ? bp[r] : 0.0f;   // bias added exactly once
            #pragma unroll
            for (int k = 0; k < 8; ++k) acc[k][r] = v;
        }
    }

    // gather-to-regs staging: slot s = t + rep*256 (s in 0..4095):
    // row = s>>3, seg = s&7 = (hqq<<1)|half -> src col = hqq*64 + step*8 + half*4
    float4 g[16];
    #pragma unroll
    for (int rep = 0; rep < 16; ++rep) {
        int s = t + (rep << 8);
        int row = s >> 3, seg = s & 7;
        g[rep] = *(const float4*)(nh + (size_t)(b0 + row) * 1024 + (c << 8)
                                  + ((seg >> 1) << 6) + ((seg & 1) << 2));
    }

    #pragma unroll 1
    for (int step = 0; step < 8; ++step) {
        __syncthreads();   // prev-step reads done before overwrite
        #pragma unroll
        for (int rep = 0; rep < 16; ++rep) {
            int s = t + (rep << 8);
            int row = s >> 3, seg = s & 7;
            *(float4*)&nh_s[row * 33 + (seg << 2)] = g[rep];
        }
        __syncthreads();
        if (step < 7) {
            #pragma unroll
            for (int rep = 0; rep < 16; ++rep) {
                int s = t + (rep << 8);
                int row = s >> 3, seg = s & 7;
                g[rep] = *(const float4*)(nh + (size_t)(b0 + row) * 1024 + (c << 8)
                                          + ((seg >> 1) << 6) + ((step + 1) << 3)
                                          + ((seg & 1) << 2));
            }
        }
        // compute: this wave's 8 h of this step
        #pragma unroll
        for (int hh = 0; hh < 8; ++hh) {
            const float4 u0 = *(const float4*)&u_s[((hq << 6) + (step << 3) + hh) << 3];
            const float4 u1 = *(const float4*)&u_s[(((hq << 6) + (step << 3) + hh) << 3) + 4];
            #pragma unroll
            for (int k = 0; k < 8; ++k) {
                const float v = nh_s[(lane + (k << 6)) * 33 + (hq << 3) + hh];
                acc[k][0] = fmaf(v, u0.x, acc[k][0]);
                acc[k][1] = fmaf(v, u0.y, acc[k][1]);
                acc[k][2] = fmaf(v, u0.z, acc[k][2]);
                acc[k][3] = fmaf(v, u0.w, acc[k][3]);
                acc[k][4] = fmaf(v, u1.x, acc[k][4]);
                acc[k][5] = fmaf(v, u1.y, acc[k][5]);
                acc[k][6] = fmaf(v, u1.z, acc[k][6]);
                acc[k][7] = fmaf(v, u1.w, acc[k][7]);
            }
        }
    }

    // reduce 4 h-quarter partials through xp (phased)
    #pragma unroll 1
    for (int ph = 0; ph < 4; ++ph) {
        if (hq == ph) {
            #pragma unroll
            for (int k = 0; k < 8; ++k) {
                float* xr = &xp[(lane + (k << 6)) * 9];
                if (ph == 0) {
                    *(float4*)&xr[0] = make_float4(acc[k][0], acc[k][1], acc[k][2], acc[k][3]);
                    *(float4*)&xr[4] = make_float4(acc[k][4], acc[k][5], acc[k][6], acc[k][7]);
                } else {
                    float4 lo = *(const float4*)&xr[0];
                    float4 hi = *(const float4*)&xr[4];
                    lo.x += acc[k][0]; lo.y += acc[k][1]; lo.z += acc[k][2]; lo.w += acc[k][3];
                    hi.x += acc[k][4]; hi.y += acc[k][5]; hi.z += acc[k][6]; hi.w += acc[k][7];
                    *(float4*)&xr[0] = lo;
                    *(float4*)&xr[4] = hi;
                }
            }
        }
        __syncthreads();
    }

    // write h_t[a][c*9 + r][b0 + b] (+ ones row), coalesced per r
    #pragma unroll 1
    for (int r = 0; r < 9; ++r) {
        #pragma unroll
        for (int rep = 0; rep < 2; ++rep) {
            int b = t + (rep << 8);
            float v = (r == 8) ? 1.0f : xp[b * 9 + r];
            h_t[((size_t)a * 36 + c * 9 + r) * 8192 + b0 + b] = v;
        }
    }
}

// ---------------- K2: chain contraction ----------------
// Block: 512 b x 1 a x 1 i-quarter; 512 thr = 8 waves (wave = r); lane owns 8
// batches b = lane+64k. T chunks (7 i, staged 6144 f uniform) double-buffered
// via 3xGLL + vmcnt(3). h2/h3 pinned (144 VGPR) under (512,2); h0/h1 from LDS
// as conflict-free b32. Per wave per i: DS ~250 cy vs VALU 1472 -> VALU-bound.
__global__ __launch_bounds__(512, 2) void k2_chain(
    const float* __restrict__ Tt, const float* __restrict__ h_t,
    float* __restrict__ risP) {
    __shared__ float tc[2][6144];   // 48 KB (4704 used/chunk; overread pad)
    __shared__ float h_s[10240];    // 40 KB ([18 q][512 b] used = 9216)
    const int t    = threadIdx.x;
    const int lane = t & 63;
    const int widr = t >> 6;        // r = widr
    const int orig = blockIdx.x;
    const int s5   = orig >> 3;
    const int combo = (orig & 7) * 8 + (s5 >> 2);  // iq-siblings share XCD
    const int iq   = s5 & 3;
    const int a    = combo & 3;
    const int bg   = combo >> 2;
    const int b0   = bg << 9;
    const int i_base = iq * 20;
    const int ni     = (iq == 3) ? 21 : 20;

    const float* Tw = Tt + (size_t)a * 54432;

    // prologue: chunk 0 (3 uniform GLLs) + h_s (5 uniform GLLs)
    {
        const float* src = Tw + (size_t)i_base * 672;
        GLL(src + 4 * t, tc[0] + 4 * t);
        GLL(src + 4 * (512 + t), tc[0] + 4 * (512 + t));
        GLL(src + 4 * (1024 + t), tc[0] + 4 * (1024 + t));
        const float* hb = h_t + (size_t)a * 36 * 8192;
        #pragma unroll
        for (int rep = 0; rep < 5; ++rep) {
            int s = t + rep * 512;            // f4 slot: q = s>>7, col4 = s&127
            GLL(hb + (size_t)(s >> 7) * 8192 + b0 + ((s & 127) << 2),
                h_s + (s << 2));
        }
    }
    // pin h2, h3 (144 VGPR) from global, coalesced per (q,k)
    float h2v[8][9], h3v[8][9];
    #pragma unroll
    for (int k = 0; k < 8; ++k) {
        #pragma unroll
        for (int q = 0; q < 9; ++q) {
            h2v[k][q] = h_t[((size_t)a * 36 + 18 + q) * 8192 + b0 + (k << 6) + lane];
            h3v[k][q] = h_t[((size_t)a * 36 + 27 + q) * 8192 + b0 + (k << 6) + lane];
        }
    }
    #pragma unroll
    for (int k = 0; k < 8; ++k) {
        #pragma unroll
        for (int q = 0; q < 9; ++q) { KEEP(h2v[k][q]); KEEP(h3v[k][q]); }
    }

    float A[8] = {0.f, 0.f, 0.f, 0.f, 0.f, 0.f, 0.f, 0.f};
    asm volatile("s_waitcnt vmcnt(0)" ::: "memory");
    __syncthreads();

    int q0 = i_base / 9, q1 = i_base - 9 * (i_base / 9);

    #pragma unroll 1
    for (int ch = 0; ch < 3; ++ch) {
        if (ch < 2) {
            const float* src = Tw + (size_t)(i_base + (ch + 1) * 7) * 672;
            float* d = tc[(ch + 1) & 1];
            GLL(src + 4 * t, d + 4 * t);
            GLL(src + 4 * (512 + t), d + 4 * (512 + t));
            GLL(src + 4 * (1024 + t), d + 4 * (1024 + t));
            asm volatile("s_waitcnt vmcnt(3)" ::: "memory");   // chunk ch landed
        } else {
            asm volatile("s_waitcnt vmcnt(0)" ::: "memory");
        }
        __builtin_amdgcn_s_barrier();
        asm volatile("" ::: "memory");

        const int ni_ch = (ni - ch * 7 < 7) ? (ni - ch * 7) : 7;
        const float* tcb = tc[ch & 1];
        #pragma unroll 1
        for (int ii = 0; ii < ni_ch; ++ii) {
            float h0k[8], h1k[8];
            #pragma unroll
            for (int k = 0; k < 8; ++k) {
                h0k[k] = h_s[q0 * 512 + (k << 6) + lane];
                h1k[k] = h_s[(9 + q1) * 512 + (k << 6) + lane];
            }
            const float* tb = tcb + ii * 672 + widr * 84;
            float dd[8] = {0.f, 0.f, 0.f, 0.f, 0.f, 0.f, 0.f, 0.f};
            #pragma unroll
            for (int jt = 0; jt < 3; ++jt) {
                float sv[28];
                #pragma unroll
                for (int m = 0; m < 7; ++m)
                    *(float4*)(sv + 4 * m) = *(const float4*)(tb + jt * 28 + 4 * m);
                #pragma unroll
                for (int k = 0; k < 8; ++k) {
                    float e0 = 0.f, e1 = 0.f, e2 = 0.f;
                    #pragma unroll
                    for (int m = 0; m < 9; ++m) {
                        e0 = fmaf(sv[m],      h3v[k][m], e0);
                        e1 = fmaf(sv[9 + m],  h3v[k][m], e1);
                        e2 = fmaf(sv[18 + m], h3v[k][m], e2);
                    }
                    dd[k] = fmaf(h2v[k][3 * jt], e0, fmaf(h2v[k][3 * jt + 1], e1,
                            fmaf(h2v[k][3 * jt + 2], e2, dd[k])));
                }
            }
            #pragma unroll
            for (int k = 0; k < 8; ++k)
                A[k] = fmaf(h0k[k] * h1k[k], dd[k], A[k]);
            if (++q1 == 9) { q1 = 0; ++q0; }
        }
        asm volatile("" ::: "memory");
        __builtin_amdgcn_s_barrier();   // buffer reuse safe next iter
    }

    #pragma unroll
    for (int k = 0; k < 8; ++k)
        risP[(size_t)iq * RIS_Q + ((size_t)a * 8192 + b0 + (k << 6) + lane) * 8 + widr] = A[k];
}

// ---------------- K3: reduce 4 iq-partials + output projection ----------------
__global__ __launch_bounds__(256, 8) void k3_out(
    const float* __restrict__ risP, const float* __restrict__ Uo,
    const float* __restrict__ bo, float* __restrict__ out) {
    __shared__ float uo_s[8192];
    __shared__ float bo_s[1024];
    __shared__ float ris_s[16 * 32];
    const int t  = threadIdx.x;
    const int b0 = blockIdx.x << 4;
    for (int idx = t; idx < 8192; idx += 256) uo_s[idx] = Uo[idx];
    for (int idx = t; idx < 1024; idx += 256) bo_s[idx] = bo[idx];
    for (int idx = t; idx < 512; idx += 256) {
        int bb = idx >> 5, rem = idx & 31, aa = rem >> 3, rr = rem & 7;
        size_t ro = ((size_t)aa * 8192 + b0 + bb) * 8 + rr;
        ris_s[bb * 32 + rem] = risP[ro] + risP[RIS_Q + ro]
                             + risP[2 * RIS_Q + ro] + risP[3 * RIS_Q + ro];
    }
    __syncthreads();
    const int a  = t >> 6;
    const int c4 = (t & 63) << 2;
    float4 u[8];
    #pragma unroll
    for (int r = 0; r < 8; ++r)
        u[r] = *(const float4*)(uo_s + (a << 11) + (r << 8) + c4);
    const float4 b4 = *(const float4*)(bo_s + (a << 8) + c4);
    #pragma unroll 4
    for (int bb = 0; bb < 16; ++bb) {
        const float* rp = ris_s + bb * 32 + a * 8;
        float4 v = b4;
        #pragma unroll
        for (int r = 0; r < 8; ++r) {
            float w = rp[r];
            v.x = fmaf(w, u[r].x, v.x); v.y = fmaf(w, u[r].y, v.y);
            v.z = fmaf(w, u[r].z, v.z); v.w = fmaf(w, u[r].w, v.w);
        }
        *(float4*)(out + (size_t)(b0 + bb) * 1024 + (a << 8) + c4) = v;
    }
}

extern "C" void kernel_launch(void* const* d_in, const int* in_sizes, int n_in,
                              void* d_out, int out_size, void* d_ws, size_t ws_size,
                              hipStream_t stream) {
    (void)in_sizes; (void)n_in; (void)out_size; (void)ws_size;
    const float* nh = (const float*)d_in[0];
    const float* U  = (const float*)d_in[1];
    const float* bi = (const float*)d_in[2];
    const float* Uo = (const float*)d_in[3];
    const float* bo = (const float*)d_in[4];
    const float* T  = (const float*)d_in[5];
    float* outp = (float*)d_out;
    float* ws   = (float*)d_ws;   // 2,445,952 floats = 9.79 MB

    t_transpose<<<(TT_ELEMS + 255) / 256, 256, 0, stream>>>(T, ws);
    k1_phasex<<<256, 256, 0, stream>>>(nh, U, bi, ws + WS_HT);
    k2_chain<<<256, 512, 0, stream>>>(ws, ws + WS_HT, ws + WS_RIS);
    k3_out<<<512, 256, 0, stream>>>(ws + WS_RIS, Uo, bo, outp);
}

// Round 9
// 102.390 us; speedup vs baseline: 1.8962x; 1.8962x over previous
//
#include <hip/hip_runtime.h>

// ---------------- constants / ws layout (floats) ----------------
#define TT_ISTRIDE 672             // Tt per-i stride = 8 r * 84 padded j
#define TT_ELEMS (4 * 81 * 672)    // 217728
#define WS_HT 217728               // h_t: [4 a][36 q][8192 b] = 1179648 floats
#define WS_RIS (217728 + 1179648)  // risP: [4 iq][4 a][8192 b][8 r] = 1048576
#define WS_UT (217728 + 1179648 + 1048576)  // Ut: [4 c][256 h][32 ar] = 32768
#define RIS_Q 262144

// Transpose T[a][q0][q1][q2][q3][r] -> Tt[a][i][r][84]; j in three 28-wide
// 16B-aligned thirds: col = jt*28 + (j - jt*27); slot 27 of each third = 0.
__global__ void t_transpose(const float* __restrict__ T, float* __restrict__ Tt) {
    int idx = blockIdx.x * 256 + threadIdx.x;
    if (idx >= TT_ELEMS) return;
    int col  = idx % 84;
    int t1   = idx / 84;
    int r    = t1 & 7;
    int rest = t1 / 8;  // a*81 + i
    int jt   = col / 28;
    int kk   = col - jt * 28;
    Tt[idx] = (kk < 27) ? T[rest * 648 + (jt * 27 + kk) * 8 + r] : 0.0f;
}

// U[c][a][h][r] -> Ut[c][h][32] with col = a*8+r (contiguous broadcast rows)
__global__ void ut_transpose(const float* __restrict__ U, float* __restrict__ Ut) {
    int idx = blockIdx.x * 256 + threadIdx.x;
    if (idx >= 32768) return;
    int col = idx & 31;
    int h   = (idx >> 5) & 255;
    int c   = idx >> 13;
    Ut[idx] = U[((((c << 2) + (col >> 3)) << 8) + h) * 8 + (col & 7)];
}

#define GLL(gsrc, ldst) __builtin_amdgcn_global_load_lds( \
    (const __attribute__((address_space(1))) void*)(gsrc), \
    (__attribute__((address_space(3))) void*)(ldst), 16, 0, 0)

#define KEEP(x) asm volatile("" : "+v"(x))

// ---------------- K1: phase X (SGPR-broadcast rewrite) ----------------
// Grid 256 x 256 thr (1 block/CU, 4 waves = 1/SIMD, all CUs busy). Wave =
// (c, ar-half) via readfirstlane -> U rows come in as s_load_dwordx16 (SGPR
// broadcast: no 1KB vector writeback, no LDS, no bank conflicts). Per h:
// 16 FMA (SGPR src0) : 1 s_load_x16. nh read per-lane as contiguous float4
// rows (every 64B line fully consumed by one lane). acc[16] ~ 50 VGPR.
__global__ __launch_bounds__(256, 4) void k1_phasex(
    const float* __restrict__ nh, const float* __restrict__ Ut,
    const float* __restrict__ bi, float* __restrict__ h_t) {
    const int t    = threadIdx.x;
    const int lane = t & 63;
    const int wv   = __builtin_amdgcn_readfirstlane(t >> 6);  // 0..3
    const int ch   = blockIdx.x & 1;
    const int bg   = blockIdx.x >> 1;
    const int cs   = (ch << 1) | (wv >> 1);   // channel c (wave-uniform SGPR)
    const int arh  = wv & 1;                  // ar half: cols arh*16..+16
    const int b    = (bg << 6) + lane;

    const float* Uc  = Ut + ((size_t)cs << 13) + (arh << 4);  // [256 h][32]
    const float* nhp = nh + ((size_t)b << 10) + (cs << 8);

    float acc[16];
    #pragma unroll
    for (int j = 0; j < 16; ++j) {
        int a = (arh << 1) + (j >> 3), r = j & 7;
        acc[j] = bi[(((cs << 2) + a) << 3) + r];
    }

    #pragma unroll 2
    for (int h4 = 0; h4 < 64; ++h4) {
        const float4 v = *(const float4*)(nhp + (h4 << 2));
        const float* up = Uc + (h4 << 7);   // 4 h rows x 32
        #pragma unroll
        for (int j = 0; j < 16; ++j) acc[j] = fmaf(v.x, up[j], acc[j]);
        #pragma unroll
        for (int j = 0; j < 16; ++j) acc[j] = fmaf(v.y, up[32 + j], acc[j]);
        #pragma unroll
        for (int j = 0; j < 16; ++j) acc[j] = fmaf(v.z, up[64 + j], acc[j]);
        #pragma unroll
        for (int j = 0; j < 16; ++j) acc[j] = fmaf(v.w, up[96 + j], acc[j]);
    }

    // h_t[a][c*9+r][b], coalesced across lanes; plus the two ones-rows
    #pragma unroll
    for (int j = 0; j < 16; ++j) {
        int a = (arh << 1) + (j >> 3), r = j & 7;
        h_t[((size_t)a * 36 + cs * 9 + r) * 8192 + b] = acc[j];
    }
    h_t[((size_t)((arh << 1) + 0) * 36 + cs * 9 + 8) * 8192 + b] = 1.0f;
    h_t[((size_t)((arh << 1) + 1) * 36 + cs * 9 + 8) * 8192 + b] = 1.0f;
}

// ---------------- K2: chain contraction (unchanged from r8) ----------------
__global__ __launch_bounds__(512, 2) void k2_chain(
    const float* __restrict__ Tt, const float* __restrict__ h_t,
    float* __restrict__ risP) {
    __shared__ float tc[2][6144];   // 48 KB (4704 used/chunk; overread pad)
    __shared__ float h_s[10240];    // 40 KB ([18 q][512 b] used = 9216)
    const int t    = threadIdx.x;
    const int lane = t & 63;
    const int widr = t >> 6;        // r = widr
    const int orig = blockIdx.x;
    const int s5   = orig >> 3;
    const int combo = (orig & 7) * 8 + (s5 >> 2);  // iq-siblings share XCD
    const int iq   = s5 & 3;
    const int a    = combo & 3;
    const int bg   = combo >> 2;
    const int b0   = bg << 9;
    const int i_base = iq * 20;
    const int ni     = (iq == 3) ? 21 : 20;

    const float* Tw = Tt + (size_t)a * 54432;

    {
        const float* src = Tw + (size_t)i_base * 672;
        GLL(src + 4 * t, tc[0] + 4 * t);
        GLL(src + 4 * (512 + t), tc[0] + 4 * (512 + t));
        GLL(src + 4 * (1024 + t), tc[0] + 4 * (1024 + t));
        const float* hb = h_t + (size_t)a * 36 * 8192;
        #pragma unroll
        for (int rep = 0; rep < 5; ++rep) {
            int s = t + rep * 512;
            GLL(hb + (size_t)(s >> 7) * 8192 + b0 + ((s & 127) << 2),
                h_s + (s << 2));
        }
    }
    float h2v[8][9], h3v[8][9];
    #pragma unroll
    for (int k = 0; k < 8; ++k) {
        #pragma unroll
        for (int q = 0; q < 9; ++q) {
            h2v[k][q] = h_t[((size_t)a * 36 + 18 + q) * 8192 + b0 + (k << 6) + lane];
            h3v[k][q] = h_t[((size_t)a * 36 + 27 + q) * 8192 + b0 + (k << 6) + lane];
        }
    }
    #pragma unroll
    for (int k = 0; k < 8; ++k) {
        #pragma unroll
        for (int q = 0; q < 9; ++q) { KEEP(h2v[k][q]); KEEP(h3v[k][q]); }
    }

    float A[8] = {0.f, 0.f, 0.f, 0.f, 0.f, 0.f, 0.f, 0.f};
    asm volatile("s_waitcnt vmcnt(0)" ::: "memory");
    __syncthreads();

    int q0 = i_base / 9, q1 = i_base - 9 * (i_base / 9);

    #pragma unroll 1
    for (int ch = 0; ch < 3; ++ch) {
        if (ch < 2) {
            const float* src = Tw + (size_t)(i_base + (ch + 1) * 7) * 672;
            float* d = tc[(ch + 1) & 1];
            GLL(src + 4 * t, d + 4 * t);
            GLL(src + 4 * (512 + t), d + 4 * (512 + t));
            GLL(src + 4 * (1024 + t), d + 4 * (1024 + t));
            asm volatile("s_waitcnt vmcnt(3)" ::: "memory");
        } else {
            asm volatile("s_waitcnt vmcnt(0)" ::: "memory");
        }
        __builtin_amdgcn_s_barrier();
        asm volatile("" ::: "memory");

        const int ni_ch = (ni - ch * 7 < 7) ? (ni - ch * 7) : 7;
        const float* tcb = tc[ch & 1];
        #pragma unroll 1
        for (int ii = 0; ii < ni_ch; ++ii) {
            float h0k[8], h1k[8];
            #pragma unroll
            for (int k = 0; k < 8; ++k) {
                h0k[k] = h_s[q0 * 512 + (k << 6) + lane];
                h1k[k] = h_s[(9 + q1) * 512 + (k << 6) + lane];
            }
            const float* tb = tcb + ii * 672 + widr * 84;
            float dd[8] = {0.f, 0.f, 0.f, 0.f, 0.f, 0.f, 0.f, 0.f};
            #pragma unroll
            for (int jt = 0; jt < 3; ++jt) {
                float sv[28];
                #pragma unroll
                for (int m = 0; m < 7; ++m)
                    *(float4*)(sv + 4 * m) = *(const float4*)(tb + jt * 28 + 4 * m);
                #pragma unroll
                for (int k = 0; k < 8; ++k) {
                    float e0 = 0.f, e1 = 0.f, e2 = 0.f;
                    #pragma unroll
                    for (int m = 0; m < 9; ++m) {
                        e0 = fmaf(sv[m],      h3v[k][m], e0);
                        e1 = fmaf(sv[9 + m],  h3v[k][m], e1);
                        e2 = fmaf(sv[18 + m], h3v[k][m], e2);
                    }
                    dd[k] = fmaf(h2v[k][3 * jt], e0, fmaf(h2v[k][3 * jt + 1], e1,
                            fmaf(h2v[k][3 * jt + 2], e2, dd[k])));
                }
            }
            #pragma unroll
            for (int k = 0; k < 8; ++k)
                A[k] = fmaf(h0k[k] * h1k[k], dd[k], A[k]);
            if (++q1 == 9) { q1 = 0; ++q0; }
        }
        asm volatile("" ::: "memory");
        __builtin_amdgcn_s_barrier();
    }

    #pragma unroll
    for (int k = 0; k < 8; ++k)
        risP[(size_t)iq * RIS_Q + ((size_t)a * 8192 + b0 + (k << 6) + lane) * 8 + widr] = A[k];
}

// ---------------- K3: reduce 4 iq-partials + output projection ----------------
__global__ __launch_bounds__(256, 8) void k3_out(
    const float* __restrict__ risP, const float* __restrict__ Uo,
    const float* __restrict__ bo, float* __restrict__ out) {
    __shared__ float uo_s[8192];
    __shared__ float bo_s[1024];
    __shared__ float ris_s[16 * 32];
    const int t  = threadIdx.x;
    const int b0 = blockIdx.x << 4;
    for (int idx = t; idx < 8192; idx += 256) uo_s[idx] = Uo[idx];
    for (int idx = t; idx < 1024; idx += 256) bo_s[idx] = bo[idx];
    for (int idx = t; idx < 512; idx += 256) {
        int bb = idx >> 5, rem = idx & 31, aa = rem >> 3, rr = rem & 7;
        size_t ro = ((size_t)aa * 8192 + b0 + bb) * 8 + rr;
        ris_s[bb * 32 + rem] = risP[ro] + risP[RIS_Q + ro]
                             + risP[2 * RIS_Q + ro] + risP[3 * RIS_Q + ro];
    }
    __syncthreads();
    const int a  = t >> 6;
    const int c4 = (t & 63) << 2;
    float4 u[8];
    #pragma unroll
    for (int r = 0; r < 8; ++r)
        u[r] = *(const float4*)(uo_s + (a << 11) + (r << 8) + c4);
    const float4 b4 = *(const float4*)(bo_s + (a << 8) + c4);
    #pragma unroll 4
    for (int bb = 0; bb < 16; ++bb) {
        const float* rp = ris_s + bb * 32 + a * 8;
        float4 v = b4;
        #pragma unroll
        for (int r = 0; r < 8; ++r) {
            float w = rp[r];
            v.x = fmaf(w, u[r].x, v.x); v.y = fmaf(w, u[r].y, v.y);
            v.z = fmaf(w, u[r].z, v.z); v.w = fmaf(w, u[r].w, v.w);
        }
        *(float4*)(out + (size_t)(b0 + bb) * 1024 + (a << 8) + c4) = v;
    }
}

extern "C" void kernel_launch(void* const* d_in, const int* in_sizes, int n_in,
                              void* d_out, int out_size, void* d_ws, size_t ws_size,
                              hipStream_t stream) {
    (void)in_sizes; (void)n_in; (void)out_size; (void)ws_size;
    const float* nh = (const float*)d_in[0];
    const float* U  = (const float*)d_in[1];
    const float* bi = (const float*)d_in[2];
    const float* Uo = (const float*)d_in[3];
    const float* bo = (const float*)d_in[4];
    const float* T  = (const float*)d_in[5];
    float* outp = (float*)d_out;
    float* ws   = (float*)d_ws;   // 2,478,720 floats = 9.91 MB

    t_transpose<<<(TT_ELEMS + 255) / 256, 256, 0, stream>>>(T, ws);
    ut_transpose<<<128, 256, 0, stream>>>(U, ws + WS_UT);
    k1_phasex<<<256, 256, 0, stream>>>(nh, ws + WS_UT, bi, ws + WS_HT);
    k2_chain<<<256, 512, 0, stream>>>(ws, ws + WS_HT, ws + WS_RIS);
    k3_out<<<512, 256, 0, stream>>>(ws + WS_RIS, Uo, bo, outp);
}

// Round 10
// 99.014 us; speedup vs baseline: 1.9609x; 1.0341x over previous
//
#include <hip/hip_runtime.h>

// ---------------- constants / ws layout (floats) ----------------
#define TT_ISTRIDE 672             // Tt per-i stride = 8 r * 84 padded j
#define TT_ELEMS (4 * 81 * 672)    // 217728
#define WS_HT 217728               // h_t: [4 a][36 q][8192 b] = 1179648 floats
#define WS_RIS (217728 + 1179648)  // risP: [4 iq][4 a][8192 b][8 r] = 1048576
#define WS_UT (217728 + 1179648 + 1048576)  // Ut: [4 c][256 h][32 ar] = 32768
#define RIS_Q 262144

// Transpose T[a][q0][q1][q2][q3][r] -> Tt[a][i][r][84]; j in three 28-wide
// 16B-aligned thirds: col = jt*28 + (j - jt*27); slot 27 of each third = 0.
__global__ void t_transpose(const float* __restrict__ T, float* __restrict__ Tt) {
    int idx = blockIdx.x * 256 + threadIdx.x;
    if (idx >= TT_ELEMS) return;
    int col  = idx % 84;
    int t1   = idx / 84;
    int r    = t1 & 7;
    int rest = t1 / 8;  // a*81 + i
    int jt   = col / 28;
    int kk   = col - jt * 28;
    Tt[idx] = (kk < 27) ? T[rest * 648 + (jt * 27 + kk) * 8 + r] : 0.0f;
}

// U[c][a][h][r] -> Ut[c][h][32] with col = a*8+r (contiguous broadcast rows)
__global__ void ut_transpose(const float* __restrict__ U, float* __restrict__ Ut) {
    int idx = blockIdx.x * 256 + threadIdx.x;
    if (idx >= 32768) return;
    int col = idx & 31;
    int h   = (idx >> 5) & 255;
    int c   = idx >> 13;
    Ut[idx] = U[((((c << 2) + (col >> 3)) << 8) + h) * 8 + (col & 7)];
}

#define GLL(gsrc, ldst) __builtin_amdgcn_global_load_lds( \
    (const __attribute__((address_space(1))) void*)(gsrc), \
    (__attribute__((address_space(3))) void*)(ldst), 16, 0, 0)

#define KEEP(x) asm volatile("" : "+v"(x))

// ---------------- K1: phase X (SGPR broadcast, wave = aggregator) ----------------
// Grid 512 = 128 bg x 4 c -> 2 blocks/CU, 2 waves/SIMD. Block: 64 b x 1 c;
// wave wv = aggregator a, lane = batch. Per h4 (4 h rows): one per-lane nh
// float4 + 2 s_load_dwordx8 of this wave's 8-col Ut slice -> 32 FMA.
// Zero LDS, acc[8] in VGPR, SGPR-broadcast only (no vector/DS writeback).
__global__ __launch_bounds__(256, 2) void k1_phasex(
    const float* __restrict__ nh, const float* __restrict__ Ut,
    const float* __restrict__ bi, float* __restrict__ h_t) {
    const int t    = threadIdx.x;
    const int lane = t & 63;
    const int wv   = __builtin_amdgcn_readfirstlane(t >> 6);  // = aggregator a
    const int cs   = blockIdx.x & 3;                          // channel c
    const int bg   = blockIdx.x >> 2;                         // 0..127
    const int b    = (bg << 6) + lane;

    const float* Uc  = Ut + ((size_t)cs << 13) + (wv << 3);   // [256 h][32], col slice
    const float* nhp = nh + ((size_t)b << 10) + (cs << 8);

    float acc[8];
    #pragma unroll
    for (int r = 0; r < 8; ++r)
        acc[r] = bi[(((cs << 2) + wv) << 3) + r];

    #pragma unroll 4
    for (int h4 = 0; h4 < 64; ++h4) {
        const float4 v = *(const float4*)(nhp + (h4 << 2));
        const float* up = Uc + (h4 << 7);   // 4 h rows x 32 cols
        #pragma unroll
        for (int r = 0; r < 8; ++r) acc[r] = fmaf(v.x, up[r],      acc[r]);
        #pragma unroll
        for (int r = 0; r < 8; ++r) acc[r] = fmaf(v.y, up[32 + r], acc[r]);
        #pragma unroll
        for (int r = 0; r < 8; ++r) acc[r] = fmaf(v.z, up[64 + r], acc[r]);
        #pragma unroll
        for (int r = 0; r < 8; ++r) acc[r] = fmaf(v.w, up[96 + r], acc[r]);
    }

    // h_t[a][c*9+r][b] (coalesced across lanes) + this wave's ones row
    #pragma unroll
    for (int r = 0; r < 8; ++r)
        h_t[((size_t)wv * 36 + cs * 9 + r) * 8192 + b] = acc[r];
    h_t[((size_t)wv * 36 + cs * 9 + 8) * 8192 + b] = 1.0f;
}

// ---------------- K2: chain contraction ----------------
// Identical to r9 EXCEPT the occupancy attribute: waves_per_eu(2,2) pins the
// allocator's occupancy target at 2 waves/EU (the LDS-imposed reality: 88KB ->
// 1 block/CU -> 8 waves), unlocking the full 256-VGPR budget so the 144
// pinned h2/h3 stay resident (r9: VGPR=128 -> 11MB scratch spill, 43% VALU).
__global__ __attribute__((amdgpu_flat_work_group_size(512, 512),
                          amdgpu_waves_per_eu(2, 2))) void k2_chain(
    const float* __restrict__ Tt, const float* __restrict__ h_t,
    float* __restrict__ risP) {
    __shared__ float tc[2][6144];   // 48 KB (4704 used/chunk; overread pad)
    __shared__ float h_s[10240];    // 40 KB ([18 q][512 b] used = 9216)
    const int t    = threadIdx.x;
    const int lane = t & 63;
    const int widr = t >> 6;        // r = widr
    const int orig = blockIdx.x;
    const int s5   = orig >> 3;
    const int combo = (orig & 7) * 8 + (s5 >> 2);  // iq-siblings share XCD
    const int iq   = s5 & 3;
    const int a    = combo & 3;
    const int bg   = combo >> 2;
    const int b0   = bg << 9;
    const int i_base = iq * 20;
    const int ni     = (iq == 3) ? 21 : 20;

    const float* Tw = Tt + (size_t)a * 54432;

    {
        const float* src = Tw + (size_t)i_base * 672;
        GLL(src + 4 * t, tc[0] + 4 * t);
        GLL(src + 4 * (512 + t), tc[0] + 4 * (512 + t));
        GLL(src + 4 * (1024 + t), tc[0] + 4 * (1024 + t));
        const float* hb = h_t + (size_t)a * 36 * 8192;
        #pragma unroll
        for (int rep = 0; rep < 5; ++rep) {
            int s = t + rep * 512;
            GLL(hb + (size_t)(s >> 7) * 8192 + b0 + ((s & 127) << 2),
                h_s + (s << 2));
        }
    }
    float h2v[8][9], h3v[8][9];
    #pragma unroll
    for (int k = 0; k < 8; ++k) {
        #pragma unroll
        for (int q = 0; q < 9; ++q) {
            h2v[k][q] = h_t[((size_t)a * 36 + 18 + q) * 8192 + b0 + (k << 6) + lane];
            h3v[k][q] = h_t[((size_t)a * 36 + 27 + q) * 8192 + b0 + (k << 6) + lane];
        }
    }
    #pragma unroll
    for (int k = 0; k < 8; ++k) {
        #pragma unroll
        for (int q = 0; q < 9; ++q) { KEEP(h2v[k][q]); KEEP(h3v[k][q]); }
    }

    float A[8] = {0.f, 0.f, 0.f, 0.f, 0.f, 0.f, 0.f, 0.f};
    asm volatile("s_waitcnt vmcnt(0)" ::: "memory");
    __syncthreads();

    int q0 = i_base / 9, q1 = i_base - 9 * (i_base / 9);

    #pragma unroll 1
    for (int ch = 0; ch < 3; ++ch) {
        if (ch < 2) {
            const float* src = Tw + (size_t)(i_base + (ch + 1) * 7) * 672;
            float* d = tc[(ch + 1) & 1];
            GLL(src + 4 * t, d + 4 * t);
            GLL(src + 4 * (512 + t), d + 4 * (512 + t));
            GLL(src + 4 * (1024 + t), d + 4 * (1024 + t));
            asm volatile("s_waitcnt vmcnt(3)" ::: "memory");
        } else {
            asm volatile("s_waitcnt vmcnt(0)" ::: "memory");
        }
        __builtin_amdgcn_s_barrier();
        asm volatile("" ::: "memory");

        const int ni_ch = (ni - ch * 7 < 7) ? (ni - ch * 7) : 7;
        const float* tcb = tc[ch & 1];
        #pragma unroll 1
        for (int ii = 0; ii < ni_ch; ++ii) {
            float h0k[8], h1k[8];
            #pragma unroll
            for (int k = 0; k < 8; ++k) {
                h0k[k] = h_s[q0 * 512 + (k << 6) + lane];
                h1k[k] = h_s[(9 + q1) * 512 + (k << 6) + lane];
            }
            const float* tb = tcb + ii * 672 + widr * 84;
            float dd[8] = {0.f, 0.f, 0.f, 0.f, 0.f, 0.f, 0.f, 0.f};
            #pragma unroll
            for (int jt = 0; jt < 3; ++jt) {
                float sv[28];
                #pragma unroll
                for (int m = 0; m < 7; ++m)
                    *(float4*)(sv + 4 * m) = *(const float4*)(tb + jt * 28 + 4 * m);
                #pragma unroll
                for (int k = 0; k < 8; ++k) {
                    float e0 = 0.f, e1 = 0.f, e2 = 0.f;
                    #pragma unroll
                    for (int m = 0; m < 9; ++m) {
                        e0 = fmaf(sv[m],      h3v[k][m], e0);
                        e1 = fmaf(sv[9 + m],  h3v[k][m], e1);
                        e2 = fmaf(sv[18 + m], h3v[k][m], e2);
                    }
                    dd[k] = fmaf(h2v[k][3 * jt], e0, fmaf(h2v[k][3 * jt + 1], e1,
                            fmaf(h2v[k][3 * jt + 2], e2, dd[k])));
                }
            }
            #pragma unroll
            for (int k = 0; k < 8; ++k)
                A[k] = fmaf(h0k[k] * h1k[k], dd[k], A[k]);
            if (++q1 == 9) { q1 = 0; ++q0; }
        }
        asm volatile("" ::: "memory");
        __builtin_amdgcn_s_barrier();
    }

    #pragma unroll
    for (int k = 0; k < 8; ++k)
        risP[(size_t)iq * RIS_Q + ((size_t)a * 8192 + b0 + (k << 6) + lane) * 8 + widr] = A[k];
}

// ---------------- K3: reduce 4 iq-partials + output projection ----------------
__global__ __launch_bounds__(256, 8) void k3_out(
    const float* __restrict__ risP, const float* __restrict__ Uo,
    const float* __restrict__ bo, float* __restrict__ out) {
    __shared__ float uo_s[8192];
    __shared__ float bo_s[1024];
    __shared__ float ris_s[16 * 32];
    const int t  = threadIdx.x;
    const int b0 = blockIdx.x << 4;
    for (int idx = t; idx < 8192; idx += 256) uo_s[idx] = Uo[idx];
    for (int idx = t; idx < 1024; idx += 256) bo_s[idx] = bo[idx];
    for (int idx = t; idx < 512; idx += 256) {
        int bb = idx >> 5, rem = idx & 31, aa = rem >> 3, rr = rem & 7;
        size_t ro = ((size_t)aa * 8192 + b0 + bb) * 8 + rr;
        ris_s[bb * 32 + rem] = risP[ro] + risP[RIS_Q + ro]
                             + risP[2 * RIS_Q + ro] + risP[3 * RIS_Q + ro];
    }
    __syncthreads();
    const int a  = t >> 6;
    const int c4 = (t & 63) << 2;
    float4 u[8];
    #pragma unroll
    for (int r = 0; r < 8; ++r)
        u[r] = *(const float4*)(uo_s + (a << 11) + (r << 8) + c4);
    const float4 b4 = *(const float4*)(bo_s + (a << 8) + c4);
    #pragma unroll 4
    for (int bb = 0; bb < 16; ++bb) {
        const float* rp = ris_s + bb * 32 + a * 8;
        float4 v = b4;
        #pragma unroll
        for (int r = 0; r < 8; ++r) {
            float w = rp[r];
            v.x = fmaf(w, u[r].x, v.x); v.y = fmaf(w, u[r].y, v.y);
            v.z = fmaf(w, u[r].z, v.z); v.w = fmaf(w, u[r].w, v.w);
        }
        *(float4*)(out + (size_t)(b0 + bb) * 1024 + (a << 8) + c4) = v;
    }
}

extern "C" void kernel_launch(void* const* d_in, const int* in_sizes, int n_in,
                              void* d_out, int out_size, void* d_ws, size_t ws_size,
                              hipStream_t stream) {
    (void)in_sizes; (void)n_in; (void)out_size; (void)ws_size;
    const float* nh = (const float*)d_in[0];
    const float* U  = (const float*)d_in[1];
    const float* bi = (const float*)d_in[2];
    const float* Uo = (const float*)d_in[3];
    const float* bo = (const float*)d_in[4];
    const float* T  = (const float*)d_in[5];
    float* outp = (float*)d_out;
    float* ws   = (float*)d_ws;   // 2,478,720 floats = 9.91 MB

    t_transpose<<<(TT_ELEMS + 255) / 256, 256, 0, stream>>>(T, ws);
    ut_transpose<<<128, 256, 0, stream>>>(U, ws + WS_UT);
    k1_phasex<<<512, 256, 0, stream>>>(nh, ws + WS_UT, bi, ws + WS_HT);
    k2_chain<<<256, 512, 0, stream>>>(ws, ws + WS_HT, ws + WS_RIS);
    k3_out<<<512, 256, 0, stream>>>(ws + WS_RIS, Uo, bo, outp);
}